// Round 11
// baseline (245.114 us; speedup 1.0000x reference)
//
#include <hip/hip_runtime.h>
#include <cstdint>

#define HDIM 256
#define MT   128      // feature rows per block (4 waves x 32 rows)
#define BD   32       // En rows per K-loop iteration
#define NSPLIT_MAX 64

typedef short bf16x8 __attribute__((ext_vector_type(8)));
typedef short bf16x4 __attribute__((ext_vector_type(4)));
typedef float f32x4  __attribute__((ext_vector_type(4)));

typedef const __attribute__((address_space(1))) short as1_short;
typedef __attribute__((address_space(3))) short as3_short;

static __device__ __forceinline__ short f2bf(float x) {
    union { float f; uint32_t u; } v; v.f = x;
    uint32_t u = v.u;
    uint32_t r = (u + 0x7fffu + ((u >> 16) & 1u)) >> 16;
    return (short)r;
}

// ---- prep (single dispatch):
//  blocks [0, nb_nrm)          : L2-normalize feature/ex_feature rows -> bf16,
//                                stored with XOR-16B-chunk swizzle
//  blocks [nb_nrm, nb_nrm+128) : transpose class reps to Rt[32][D] (col C = 1.0
//                                -> intensity falls out of the echo GEMM)
__global__ __launch_bounds__(256) void prep_kernel(const float* __restrict__ fsrc,
                                                   const float* __restrict__ esrc,
                                                   const float* __restrict__ reps,
                                                   short* __restrict__ dst,
                                                   short* __restrict__ rt,
                                                   int N, int rows_total,
                                                   int D, int C, int nb_nrm) {
    __shared__ float lds[128][29];                    // +1 pad col
    const int tid = threadIdx.x;
    if ((int)blockIdx.x < nb_nrm) {
        int wv = tid >> 6;
        int lane = tid & 63;
        int row = blockIdx.x * 4 + wv;
        if (row >= rows_total) return;
        const float* src = (row < N) ? (fsrc + (size_t)row * HDIM)
                                     : (esrc + (size_t)(row - N) * HDIM);
        const float4 v = *(const float4*)(src + lane * 4);
        float ss = v.x * v.x + v.y * v.y + v.z * v.z + v.w * v.w;
        #pragma unroll
        for (int m = 1; m < 64; m <<= 1) ss += __shfl_xor(ss, m, 64);
        float scale = 1.0f / fmaxf(sqrtf(ss), 1e-12f);
        short4 o;
        o.x = f2bf(v.x * scale); o.y = f2bf(v.y * scale);
        o.z = f2bf(v.z * scale); o.w = f2bf(v.w * scale);
        int chunk = (lane >> 1) ^ (row & 7);          // swizzled 16B-chunk index
        *(short4*)(dst + (size_t)row * HDIM + chunk * 8 + (lane & 1) * 4) = o;
    } else {
        const int bx = blockIdx.x - nb_nrm;           // 0..127
        const int d0 = bx * 128;
        const int total = 128 * C;
        const float* src = reps + (size_t)d0 * C;
        for (int i = tid; i < total; i += 256)
            lds[i / C][i % C] = src[i];               // coalesced load
        __syncthreads();
        const int c = tid >> 3;                       // 0..31
        const int dsub = (tid & 7) * 16;              // 16 d per thread
        short* dstp = rt + (size_t)c * D + d0 + dsub;
        #pragma unroll
        for (int j0 = 0; j0 < 16; j0 += 4) {
            short4 o;
            float v0, v1, v2, v3;
            if (c < C) {
                v0 = lds[dsub + j0 + 0][c]; v1 = lds[dsub + j0 + 1][c];
                v2 = lds[dsub + j0 + 2][c]; v3 = lds[dsub + j0 + 3][c];
            } else {
                float f = (c == C) ? 1.0f : 0.0f;     // ones column -> intensity
                v0 = v1 = v2 = v3 = f;
            }
            o.x = f2bf(v0); o.y = f2bf(v1); o.z = f2bf(v2); o.w = f2bf(v3);
            *(short4*)(dstp + j0) = o;                // coalesced store
        }
    }
}

// ---- fused (R9 body, higher TLP): GEMM1 computes S^T via operand-swapped MFMA
// (A=En, B=Fn); activated tile is already in 16x16x16 B-operand layout (C/D
// layout == B layout for K=16 MFMA) -> GEMM2 echo^T with NO LDS round-trip.
// SPLITS=64 + (256,5): 5 blocks/CU (LDS 32 KB caps at 5), 20 waves/CU.
// XOR de-swizzle stays in per-lane addresses (r5 bug). ----
__global__ __launch_bounds__(256, 5) void fused_kernel(const short* __restrict__ Fn,
                                                       const short* __restrict__ En,
                                                       const short* __restrict__ Rt,
                                                       const int* __restrict__ pptr,
                                                       float* __restrict__ partial,
                                                       int N, int D, int C, int Dchunk) {
    __shared__ __align__(16) short lds_en[2][BD * HDIM];   // 2 x 16 KB double buffer

    const int tid  = threadIdx.x;
    const int lane = tid & 63;
    const int wv   = tid >> 6;
    const int q    = lane >> 4;
    const int l    = lane & 15;
    const int p    = pptr[0];

    const int Mbase = blockIdx.y * MT;
    const int dbase = blockIdx.x * Dchunk;

    const f32x4 zf = {0.0f, 0.0f, 0.0f, 0.0f};

    // Fn fragments (B-operand of GEMM1): per-lane de-swizzled addresses.
    bf16x8 afrag[2][8];
    #pragma unroll
    for (int fn = 0; fn < 2; ++fn) {
        const short* rowp = Fn + (size_t)(Mbase + wv * 32 + fn * 16 + l) * HDIM;
        #pragma unroll
        for (int ks = 0; ks < 8; ++ks)
            afrag[fn][ks] = *(const bf16x8*)(rowp + (((ks * 4 + q) ^ (l & 7)) << 3));
    }

    // echo^T accumulators: [f-tile][c-tile], C/D layout col=f(l), row=c(q*4+r)
    f32x4 echo_acc[2][2];
    echo_acc[0][0] = zf; echo_acc[0][1] = zf;
    echo_acc[1][0] = zf; echo_acc[1][1] = zf;

    const int iters = Dchunk / BD;

    #define STAGE(buf_, it_)                                                        \
        {                                                                           \
            const short* gbase = En + (size_t)(dbase + (it_) * BD) * HDIM + tid * 8;\
            _Pragma("unroll")                                                       \
            for (int i = 0; i < 4; ++i) {                                           \
                as3_short* lp = (as3_short*)(lds_en[buf_] + (i * 256 + wv * 64) * 8);\
                __builtin_amdgcn_global_load_lds((as1_short*)(gbase + i * 2048),    \
                                                 lp, 16, 0, 0);                     \
            }                                                                       \
        }

    STAGE(0, 0)

    const short* rtp = Rt + (size_t)l * D + q * 4;    // c-tile 0 row; +16*D for tile 1

    for (int it = 0; it < iters; ++it) {
        const int buf = it & 1;
        __syncthreads();                 // stage(it) landed; all waves done with buf^1
        if (it + 1 < iters) STAGE(buf ^ 1, it + 1)

        const int d0 = dbase + it * BD;

        // GEMM1: S^T tiles [en=d-block][fn=f-tile], 32(D) x 32(M) per wave, K=256
        f32x4 sT[2][2];
        sT[0][0] = zf; sT[0][1] = zf; sT[1][0] = zf; sT[1][1] = zf;
        #pragma unroll
        for (int ks = 0; ks < 8; ++ks) {
            #pragma unroll
            for (int en = 0; en < 2; ++en) {
                const int row  = en * 16 + l;
                const int slot = (ks * 4 + q) ^ (l & 7);
                bf16x8 ef = *(const bf16x8*)(lds_en[buf] + row * HDIM + slot * 8);
                sT[en][0] = __builtin_amdgcn_mfma_f32_16x16x32_bf16(ef, afrag[0][ks], sT[en][0], 0, 0, 0);
                sT[en][1] = __builtin_amdgcn_mfma_f32_16x16x32_bf16(ef, afrag[1][ks], sT[en][1], 0, 0, 0);
            }
        }

        // activation in-register -> packed bf16x4 (already 16x16x16 B-layout)
        bf16x4 pfrag[2][2];              // [f-tile][d-block]
        #pragma unroll
        for (int en = 0; en < 2; ++en) {
            #pragma unroll
            for (int fn = 0; fn < 2; ++fn) {
                bf16x4 pf;
                #pragma unroll
                for (int r = 0; r < 4; ++r) {
                    float sv = sT[en][fn][r];
                    float a;
                    if (p == 3)      a = sv * sv * sv;
                    else if (p == 1) a = sv;
                    else if (p == 2) a = sv * fabsf(sv);
                    else             a = copysignf(powf(fabsf(sv), (float)p), sv);
                    pf[r] = f2bf(a);
                }
                pfrag[fn][en] = pf;
            }
        }

        // GEMM2: echo^T += Rt_frag(A) * a^T(B), 16x16x16, K=32 via 2 d-blocks
        #pragma unroll
        for (int dblk = 0; dblk < 2; ++dblk) {
            const int doff = d0 + dblk * 16;
            bf16x4 rt0 = *(const bf16x4*)(rtp + doff);              // c-tile 0
            bf16x4 rt1 = *(const bf16x4*)(rtp + (size_t)16 * D + doff); // c-tile 1
            #pragma unroll
            for (int fn = 0; fn < 2; ++fn) {
                echo_acc[fn][0] = __builtin_amdgcn_mfma_f32_16x16x16bf16_1k(rt0, pfrag[fn][dblk], echo_acc[fn][0], 0, 0, 0);
                echo_acc[fn][1] = __builtin_amdgcn_mfma_f32_16x16x16bf16_1k(rt1, pfrag[fn][dblk], echo_acc[fn][1], 0, 0, 0);
            }
        }
    }

    // Epilogue: echo^T C-layout (col f = l, rows c = ct*16 + q*4 + r) -> one
    // float4 store per (f-tile, c-tile); reduce kernel ignores c > C.
    #pragma unroll
    for (int fn = 0; fn < 2; ++fn) {
        const int grow = Mbase + wv * 32 + fn * 16 + l;
        float* rowp = partial + ((size_t)blockIdx.x * N + grow) * 32 + q * 4;
        *(f32x4*)(rowp)      = echo_acc[fn][0];
        *(f32x4*)(rowp + 16) = echo_acc[fn][1];
    }
}

// ---- reduce: sum partials over splits; col<C -> echo, col==C -> intensity ----
__global__ __launch_bounds__(256) void reduce_kernel(const float* __restrict__ partial,
                                                     float* __restrict__ echo,
                                                     float* __restrict__ inten,
                                                     int N, int splits, int C) {
    int t = blockIdx.x * 256 + threadIdx.x;    // N*32 threads
    int row = t >> 5, c = t & 31;
    if (row >= N || c > C) return;
    float s = 0.0f;
    for (int k = 0; k < splits; ++k)
        s += partial[((size_t)k * N + (size_t)row) * 32 + c];
    if (c < C) echo[(size_t)row * C + c] = s;
    else       inten[row] = s;
}

extern "C" void kernel_launch(void* const* d_in, const int* in_sizes, int n_in,
                              void* d_out, int out_size, void* d_ws, size_t ws_size,
                              hipStream_t stream) {
    const int N = in_sizes[0] / HDIM;       // 4096
    const int D = in_sizes[1] / HDIM;       // 16384
    const int C = in_sizes[2] / D;          // 28

    const float* feat = (const float*)d_in[0];
    const float* exf  = (const float*)d_in[1];
    const float* reps = (const float*)d_in[2];
    const int*   p    = (const int*)d_in[3];

    short* Fn = (short*)d_ws;                          // [N][256] bf16 (swizzled)
    short* En = Fn + (size_t)N * HDIM;                 // [D][256] bf16 (swizzled)
    short* Rt = En + (size_t)D * HDIM;                 // [32][D] bf16 (col C = 1.0)
    float* partial = (float*)(Rt + (size_t)32 * D);    // [splits][N][32] f32

    const size_t base_bytes = ((size_t)(N + D) * HDIM + (size_t)32 * D) * 2;
    int splits = NSPLIT_MAX;
    while (splits > 1 &&
           base_bytes + (size_t)splits * N * 32 * 4 > ws_size) splits >>= 1;

    float* echo  = (float*)d_out;
    float* inten = echo + (size_t)N * C;

    const int nb_nrm = (N + D) / 4;
    hipLaunchKernelGGL(prep_kernel, dim3(nb_nrm + D / 128), dim3(256), 0, stream,
                       feat, exf, reps, Fn, Rt, N, N + D, D, C, nb_nrm);

    const int Dchunk = D / splits;
    hipLaunchKernelGGL(fused_kernel, dim3(splits, N / MT), dim3(256), 0, stream,
                       Fn, En, Rt, p, partial, N, D, C, Dchunk);

    hipLaunchKernelGGL(reduce_kernel, dim3(N * 32 / 256), dim3(256), 0, stream,
                       partial, echo, inten, N, splits, C);
}

// Round 12
// 157.855 us; speedup vs baseline: 1.5528x; 1.5528x over previous
//
#include <hip/hip_runtime.h>
#include <cstdint>

#define HDIM 256
#define MT   128      // feature rows per block (4 waves x 32 rows)
#define BD   32       // En rows per K-loop iteration
#define NSPLIT_MAX 64

typedef short bf16x8 __attribute__((ext_vector_type(8)));
typedef short bf16x4 __attribute__((ext_vector_type(4)));
typedef float f32x4  __attribute__((ext_vector_type(4)));

typedef const __attribute__((address_space(1))) short as1_short;
typedef __attribute__((address_space(3))) short as3_short;

static __device__ __forceinline__ short f2bf(float x) {
    union { float f; uint32_t u; } v; v.f = x;
    uint32_t u = v.u;
    uint32_t r = (u + 0x7fffu + ((u >> 16) & 1u)) >> 16;
    return (short)r;
}

// ---- prep (single dispatch):
//  blocks [0, nb_nrm)          : L2-normalize feature/ex_feature rows -> bf16,
//                                stored with XOR-16B-chunk swizzle
//  blocks [nb_nrm, nb_nrm+128) : transpose class reps to Rt[32][D] (col C = 1.0
//                                -> intensity falls out of the echo GEMM)
__global__ __launch_bounds__(256) void prep_kernel(const float* __restrict__ fsrc,
                                                   const float* __restrict__ esrc,
                                                   const float* __restrict__ reps,
                                                   short* __restrict__ dst,
                                                   short* __restrict__ rt,
                                                   int N, int rows_total,
                                                   int D, int C, int nb_nrm) {
    __shared__ float lds[128][29];                    // +1 pad col
    const int tid = threadIdx.x;
    if ((int)blockIdx.x < nb_nrm) {
        int wv = tid >> 6;
        int lane = tid & 63;
        int row = blockIdx.x * 4 + wv;
        if (row >= rows_total) return;
        const float* src = (row < N) ? (fsrc + (size_t)row * HDIM)
                                     : (esrc + (size_t)(row - N) * HDIM);
        const float4 v = *(const float4*)(src + lane * 4);
        float ss = v.x * v.x + v.y * v.y + v.z * v.z + v.w * v.w;
        #pragma unroll
        for (int m = 1; m < 64; m <<= 1) ss += __shfl_xor(ss, m, 64);
        float scale = 1.0f / fmaxf(sqrtf(ss), 1e-12f);
        short4 o;
        o.x = f2bf(v.x * scale); o.y = f2bf(v.y * scale);
        o.z = f2bf(v.z * scale); o.w = f2bf(v.w * scale);
        int chunk = (lane >> 1) ^ (row & 7);          // swizzled 16B-chunk index
        *(short4*)(dst + (size_t)row * HDIM + chunk * 8 + (lane & 1) * 4) = o;
    } else {
        const int bx = blockIdx.x - nb_nrm;           // 0..127
        const int d0 = bx * 128;
        const int total = 128 * C;
        const float* src = reps + (size_t)d0 * C;
        for (int i = tid; i < total; i += 256)
            lds[i / C][i % C] = src[i];               // coalesced load
        __syncthreads();
        const int c = tid >> 3;                       // 0..31
        const int dsub = (tid & 7) * 16;              // 16 d per thread
        short* dstp = rt + (size_t)c * D + d0 + dsub;
        #pragma unroll
        for (int j0 = 0; j0 < 16; j0 += 4) {
            short4 o;
            float v0, v1, v2, v3;
            if (c < C) {
                v0 = lds[dsub + j0 + 0][c]; v1 = lds[dsub + j0 + 1][c];
                v2 = lds[dsub + j0 + 2][c]; v3 = lds[dsub + j0 + 3][c];
            } else {
                float f = (c == C) ? 1.0f : 0.0f;     // ones column -> intensity
                v0 = v1 = v2 = v3 = f;
            }
            o.x = f2bf(v0); o.y = f2bf(v1); o.z = f2bf(v2); o.w = f2bf(v3);
            *(short4*)(dstp + j0) = o;                // coalesced store
        }
    }
}

// ---- fused (R9 body): GEMM1 computes S^T via operand-swapped MFMA (A=En,
// B=Fn); activated tile is already in 16x16x16 B-operand layout (C/D layout ==
// B layout for K=16 MFMA) -> GEMM2 echo^T with NO LDS round-trip.
// TLP comes from GRID size (2048 blocks), NOT the launch_bounds arg: residency
// is set by actual resources (VGPR 64, LDS 32 KB -> 5 blocks/CU). (256,5)
// capped VGPRs at ~96 and spilled in-loop (R11: FETCH 392 MB) — keep (256,4),
// the allocator budget that gives spill-free VGPR 64 (R9).
// XOR de-swizzle stays in per-lane addresses (r5 bug). ----
__global__ __launch_bounds__(256, 4) void fused_kernel(const short* __restrict__ Fn,
                                                       const short* __restrict__ En,
                                                       const short* __restrict__ Rt,
                                                       const int* __restrict__ pptr,
                                                       float* __restrict__ partial,
                                                       int N, int D, int C, int Dchunk) {
    __shared__ __align__(16) short lds_en[2][BD * HDIM];   // 2 x 16 KB double buffer

    const int tid  = threadIdx.x;
    const int lane = tid & 63;
    const int wv   = tid >> 6;
    const int q    = lane >> 4;
    const int l    = lane & 15;
    const int p    = pptr[0];

    const int Mbase = blockIdx.y * MT;
    const int dbase = blockIdx.x * Dchunk;

    const f32x4 zf = {0.0f, 0.0f, 0.0f, 0.0f};

    // Fn fragments (B-operand of GEMM1): per-lane de-swizzled addresses.
    bf16x8 afrag[2][8];
    #pragma unroll
    for (int fn = 0; fn < 2; ++fn) {
        const short* rowp = Fn + (size_t)(Mbase + wv * 32 + fn * 16 + l) * HDIM;
        #pragma unroll
        for (int ks = 0; ks < 8; ++ks)
            afrag[fn][ks] = *(const bf16x8*)(rowp + (((ks * 4 + q) ^ (l & 7)) << 3));
    }

    // echo^T accumulators: [f-tile][c-tile], C/D layout col=f(l), row=c(q*4+r)
    f32x4 echo_acc[2][2];
    echo_acc[0][0] = zf; echo_acc[0][1] = zf;
    echo_acc[1][0] = zf; echo_acc[1][1] = zf;

    const int iters = Dchunk / BD;

    #define STAGE(buf_, it_)                                                        \
        {                                                                           \
            const short* gbase = En + (size_t)(dbase + (it_) * BD) * HDIM + tid * 8;\
            _Pragma("unroll")                                                       \
            for (int i = 0; i < 4; ++i) {                                           \
                as3_short* lp = (as3_short*)(lds_en[buf_] + (i * 256 + wv * 64) * 8);\
                __builtin_amdgcn_global_load_lds((as1_short*)(gbase + i * 2048),    \
                                                 lp, 16, 0, 0);                     \
            }                                                                       \
        }

    STAGE(0, 0)

    const short* rtp = Rt + (size_t)l * D + q * 4;    // c-tile 0 row; +16*D for tile 1

    for (int it = 0; it < iters; ++it) {
        const int buf = it & 1;
        __syncthreads();                 // stage(it) landed; all waves done with buf^1
        if (it + 1 < iters) STAGE(buf ^ 1, it + 1)

        const int d0 = dbase + it * BD;

        // GEMM1: S^T tiles [en=d-block][fn=f-tile], 32(D) x 32(M) per wave, K=256
        f32x4 sT[2][2];
        sT[0][0] = zf; sT[0][1] = zf; sT[1][0] = zf; sT[1][1] = zf;
        #pragma unroll
        for (int ks = 0; ks < 8; ++ks) {
            #pragma unroll
            for (int en = 0; en < 2; ++en) {
                const int row  = en * 16 + l;
                const int slot = (ks * 4 + q) ^ (l & 7);
                bf16x8 ef = *(const bf16x8*)(lds_en[buf] + row * HDIM + slot * 8);
                sT[en][0] = __builtin_amdgcn_mfma_f32_16x16x32_bf16(ef, afrag[0][ks], sT[en][0], 0, 0, 0);
                sT[en][1] = __builtin_amdgcn_mfma_f32_16x16x32_bf16(ef, afrag[1][ks], sT[en][1], 0, 0, 0);
            }
        }

        // activation in-register -> packed bf16x4 (already 16x16x16 B-layout)
        bf16x4 pfrag[2][2];              // [f-tile][d-block]
        #pragma unroll
        for (int en = 0; en < 2; ++en) {
            #pragma unroll
            for (int fn = 0; fn < 2; ++fn) {
                bf16x4 pf;
                #pragma unroll
                for (int r = 0; r < 4; ++r) {
                    float sv = sT[en][fn][r];
                    float a;
                    if (p == 3)      a = sv * sv * sv;
                    else if (p == 1) a = sv;
                    else if (p == 2) a = sv * fabsf(sv);
                    else             a = copysignf(powf(fabsf(sv), (float)p), sv);
                    pf[r] = f2bf(a);
                }
                pfrag[fn][en] = pf;
            }
        }

        // GEMM2: echo^T += Rt_frag(A) * a^T(B), 16x16x16, K=32 via 2 d-blocks
        #pragma unroll
        for (int dblk = 0; dblk < 2; ++dblk) {
            const int doff = d0 + dblk * 16;
            bf16x4 rt0 = *(const bf16x4*)(rtp + doff);              // c-tile 0
            bf16x4 rt1 = *(const bf16x4*)(rtp + (size_t)16 * D + doff); // c-tile 1
            #pragma unroll
            for (int fn = 0; fn < 2; ++fn) {
                echo_acc[fn][0] = __builtin_amdgcn_mfma_f32_16x16x16bf16_1k(rt0, pfrag[fn][dblk], echo_acc[fn][0], 0, 0, 0);
                echo_acc[fn][1] = __builtin_amdgcn_mfma_f32_16x16x16bf16_1k(rt1, pfrag[fn][dblk], echo_acc[fn][1], 0, 0, 0);
            }
        }
    }

    // Epilogue: echo^T C-layout (col f = l, rows c = ct*16 + q*4 + r) -> one
    // float4 store per (f-tile, c-tile); reduce kernel ignores c > C.
    #pragma unroll
    for (int fn = 0; fn < 2; ++fn) {
        const int grow = Mbase + wv * 32 + fn * 16 + l;
        float* rowp = partial + ((size_t)blockIdx.x * N + grow) * 32 + q * 4;
        *(f32x4*)(rowp)      = echo_acc[fn][0];
        *(f32x4*)(rowp + 16) = echo_acc[fn][1];
    }
}

// ---- reduce: sum partials over splits; col<C -> echo, col==C -> intensity ----
__global__ __launch_bounds__(256) void reduce_kernel(const float* __restrict__ partial,
                                                     float* __restrict__ echo,
                                                     float* __restrict__ inten,
                                                     int N, int splits, int C) {
    int t = blockIdx.x * 256 + threadIdx.x;    // N*32 threads
    int row = t >> 5, c = t & 31;
    if (row >= N || c > C) return;
    float s = 0.0f;
    for (int k = 0; k < splits; ++k)
        s += partial[((size_t)k * N + (size_t)row) * 32 + c];
    if (c < C) echo[(size_t)row * C + c] = s;
    else       inten[row] = s;
}

extern "C" void kernel_launch(void* const* d_in, const int* in_sizes, int n_in,
                              void* d_out, int out_size, void* d_ws, size_t ws_size,
                              hipStream_t stream) {
    const int N = in_sizes[0] / HDIM;       // 4096
    const int D = in_sizes[1] / HDIM;       // 16384
    const int C = in_sizes[2] / D;          // 28

    const float* feat = (const float*)d_in[0];
    const float* exf  = (const float*)d_in[1];
    const float* reps = (const float*)d_in[2];
    const int*   p    = (const int*)d_in[3];

    short* Fn = (short*)d_ws;                          // [N][256] bf16 (swizzled)
    short* En = Fn + (size_t)N * HDIM;                 // [D][256] bf16 (swizzled)
    short* Rt = En + (size_t)D * HDIM;                 // [32][D] bf16 (col C = 1.0)
    float* partial = (float*)(Rt + (size_t)32 * D);    // [splits][N][32] f32

    const size_t base_bytes = ((size_t)(N + D) * HDIM + (size_t)32 * D) * 2;
    int splits = NSPLIT_MAX;
    while (splits > 1 &&
           base_bytes + (size_t)splits * N * 32 * 4 > ws_size) splits >>= 1;

    float* echo  = (float*)d_out;
    float* inten = echo + (size_t)N * C;

    const int nb_nrm = (N + D) / 4;
    hipLaunchKernelGGL(prep_kernel, dim3(nb_nrm + D / 128), dim3(256), 0, stream,
                       feat, exf, reps, Fn, Rt, N, N + D, D, C, nb_nrm);

    const int Dchunk = D / splits;
    hipLaunchKernelGGL(fused_kernel, dim3(splits, N / MT), dim3(256), 0, stream,
                       Fn, En, Rt, p, partial, N, D, C, Dchunk);

    hipLaunchKernelGGL(reduce_kernel, dim3(N * 32 / 256), dim3(256), 0, stream,
                       partial, echo, inten, N, splits, C);
}

// Round 13
// 143.578 us; speedup vs baseline: 1.7072x; 1.0994x over previous
//
#include <hip/hip_runtime.h>
#include <cstdint>

#define HDIM 256
#define MT   256      // feature rows per block (4 waves x 64 rows)
#define BD   32       // En rows per K-loop iteration
#define NSPLIT_MAX 32

typedef short bf16x8 __attribute__((ext_vector_type(8)));
typedef short bf16x4 __attribute__((ext_vector_type(4)));
typedef float f32x4  __attribute__((ext_vector_type(4)));

typedef const __attribute__((address_space(1))) short as1_short;
typedef __attribute__((address_space(3))) short as3_short;

static __device__ __forceinline__ short f2bf(float x) {
    union { float f; uint32_t u; } v; v.f = x;
    uint32_t u = v.u;
    uint32_t r = (u + 0x7fffu + ((u >> 16) & 1u)) >> 16;
    return (short)r;
}

// ---- prep (single dispatch):
//  blocks [0, nb_nrm)          : L2-normalize feature/ex_feature rows -> bf16,
//                                stored with XOR-16B-chunk swizzle
//  blocks [nb_nrm, nb_nrm+128) : transpose class reps to Rt[32][D] (col C = 1.0
//                                -> intensity falls out of the echo GEMM)
__global__ __launch_bounds__(256) void prep_kernel(const float* __restrict__ fsrc,
                                                   const float* __restrict__ esrc,
                                                   const float* __restrict__ reps,
                                                   short* __restrict__ dst,
                                                   short* __restrict__ rt,
                                                   int N, int rows_total,
                                                   int D, int C, int nb_nrm) {
    __shared__ float lds[128][29];                    // +1 pad col
    const int tid = threadIdx.x;
    if ((int)blockIdx.x < nb_nrm) {
        int wv = tid >> 6;
        int lane = tid & 63;
        int row = blockIdx.x * 4 + wv;
        if (row >= rows_total) return;
        const float* src = (row < N) ? (fsrc + (size_t)row * HDIM)
                                     : (esrc + (size_t)(row - N) * HDIM);
        const float4 v = *(const float4*)(src + lane * 4);
        float ss = v.x * v.x + v.y * v.y + v.z * v.z + v.w * v.w;
        #pragma unroll
        for (int m = 1; m < 64; m <<= 1) ss += __shfl_xor(ss, m, 64);
        float scale = 1.0f / fmaxf(sqrtf(ss), 1e-12f);
        short4 o;
        o.x = f2bf(v.x * scale); o.y = f2bf(v.y * scale);
        o.z = f2bf(v.z * scale); o.w = f2bf(v.w * scale);
        int chunk = (lane >> 1) ^ (row & 7);          // swizzled 16B-chunk index
        *(short4*)(dst + (size_t)row * HDIM + chunk * 8 + (lane & 1) * 4) = o;
    } else {
        const int bx = blockIdx.x - nb_nrm;           // 0..127
        const int d0 = bx * 128;
        const int total = 128 * C;
        const float* src = reps + (size_t)d0 * C;
        for (int i = tid; i < total; i += 256)
            lds[i / C][i % C] = src[i];               // coalesced load
        __syncthreads();
        const int c = tid >> 3;                       // 0..31
        const int dsub = (tid & 7) * 16;              // 16 d per thread
        short* dstp = rt + (size_t)c * D + d0 + dsub;
        #pragma unroll
        for (int j0 = 0; j0 < 16; j0 += 4) {
            short4 o;
            float v0, v1, v2, v3;
            if (c < C) {
                v0 = lds[dsub + j0 + 0][c]; v1 = lds[dsub + j0 + 1][c];
                v2 = lds[dsub + j0 + 2][c]; v3 = lds[dsub + j0 + 3][c];
            } else {
                float f = (c == C) ? 1.0f : 0.0f;     // ones column -> intensity
                v0 = v1 = v2 = v3 = f;
            }
            o.x = f2bf(v0); o.y = f2bf(v1); o.z = f2bf(v2); o.w = f2bf(v3);
            *(short4*)(dstp + j0) = o;                // coalesced store
        }
    }
}

// ---- fused (R9 body, 2x M-reuse): wave owns 64 M-rows -> each 16B LDS B-read
// feeds 4 MFMAs (was 2), halving LDS B-traffic (the measured pipe ceiling).
// GEMM1 computes S^T (A=En, B=Fn); activated tile is already in 16x16x16
// B-operand layout -> GEMM2 echo^T with no LDS round-trip. (256,2): 2 blocks/CU,
// grid 512 = exact co-residency; 256-VGPR budget holds ~230 live regs.
// XOR de-swizzle stays in per-lane addresses (r5 bug). ----
__global__ __launch_bounds__(256, 2) void fused_kernel(const short* __restrict__ Fn,
                                                       const short* __restrict__ En,
                                                       const short* __restrict__ Rt,
                                                       const int* __restrict__ pptr,
                                                       float* __restrict__ partial,
                                                       int N, int D, int C, int Dchunk) {
    __shared__ __align__(16) short lds_en[2][BD * HDIM];   // 2 x 16 KB double buffer

    const int tid  = threadIdx.x;
    const int lane = tid & 63;
    const int wv   = tid >> 6;
    const int q    = lane >> 4;
    const int l    = lane & 15;
    const int p    = pptr[0];

    const int Mbase = blockIdx.y * MT;
    const int dbase = blockIdx.x * Dchunk;

    const f32x4 zf = {0.0f, 0.0f, 0.0f, 0.0f};

    // Fn fragments (B-operand of GEMM1), 4 f-tiles of 16 rows per wave.
    bf16x8 afrag[4][8];
    #pragma unroll
    for (int fn = 0; fn < 4; ++fn) {
        const short* rowp = Fn + (size_t)(Mbase + wv * 64 + fn * 16 + l) * HDIM;
        #pragma unroll
        for (int ks = 0; ks < 8; ++ks)
            afrag[fn][ks] = *(const bf16x8*)(rowp + (((ks * 4 + q) ^ (l & 7)) << 3));
    }

    // echo^T accumulators: [f-tile][c-tile]
    f32x4 echo_acc[4][2];
    #pragma unroll
    for (int fn = 0; fn < 4; ++fn) { echo_acc[fn][0] = zf; echo_acc[fn][1] = zf; }

    const int iters = Dchunk / BD;

    #define STAGE(buf_, it_)                                                        \
        {                                                                           \
            const short* gbase = En + (size_t)(dbase + (it_) * BD) * HDIM + tid * 8;\
            _Pragma("unroll")                                                       \
            for (int i = 0; i < 4; ++i) {                                           \
                as3_short* lp = (as3_short*)(lds_en[buf_] + (i * 256 + wv * 64) * 8);\
                __builtin_amdgcn_global_load_lds((as1_short*)(gbase + i * 2048),    \
                                                 lp, 16, 0, 0);                     \
            }                                                                       \
        }

    STAGE(0, 0)

    const short* rtp = Rt + (size_t)l * D + q * 4;    // c-tile 0 row; +16*D for tile 1

    for (int it = 0; it < iters; ++it) {
        const int buf = it & 1;
        __syncthreads();                 // stage(it) landed; all waves done with buf^1
        if (it + 1 < iters) STAGE(buf ^ 1, it + 1)

        const int d0 = dbase + it * BD;

        // GEMM1: S^T tiles [en=d-block][fn=f-tile], 32(D) x 64(M) per wave, K=256
        f32x4 sT[2][4];
        #pragma unroll
        for (int en = 0; en < 2; ++en)
            #pragma unroll
            for (int fn = 0; fn < 4; ++fn) sT[en][fn] = zf;

        #pragma unroll
        for (int ks = 0; ks < 8; ++ks) {
            #pragma unroll
            for (int en = 0; en < 2; ++en) {
                const int row  = en * 16 + l;
                const int slot = (ks * 4 + q) ^ (l & 7);
                bf16x8 ef = *(const bf16x8*)(lds_en[buf] + row * HDIM + slot * 8);
                #pragma unroll
                for (int fn = 0; fn < 4; ++fn)
                    sT[en][fn] = __builtin_amdgcn_mfma_f32_16x16x32_bf16(ef, afrag[fn][ks], sT[en][fn], 0, 0, 0);
            }
        }

        // activation in-register -> packed bf16x4 (already 16x16x16 B-layout)
        bf16x4 pfrag[4][2];              // [f-tile][d-block]
        #pragma unroll
        for (int en = 0; en < 2; ++en) {
            #pragma unroll
            for (int fn = 0; fn < 4; ++fn) {
                bf16x4 pf;
                #pragma unroll
                for (int r = 0; r < 4; ++r) {
                    float sv = sT[en][fn][r];
                    float a;
                    if (p == 3)      a = sv * sv * sv;
                    else if (p == 1) a = sv;
                    else if (p == 2) a = sv * fabsf(sv);
                    else             a = copysignf(powf(fabsf(sv), (float)p), sv);
                    pf[r] = f2bf(a);
                }
                pfrag[fn][en] = pf;
            }
        }

        // GEMM2: echo^T += Rt_frag(A) * a^T(B), 16x16x16, K=32 via 2 d-blocks
        #pragma unroll
        for (int dblk = 0; dblk < 2; ++dblk) {
            const int doff = d0 + dblk * 16;
            bf16x4 rt0 = *(const bf16x4*)(rtp + doff);              // c-tile 0
            bf16x4 rt1 = *(const bf16x4*)(rtp + (size_t)16 * D + doff); // c-tile 1
            #pragma unroll
            for (int fn = 0; fn < 4; ++fn) {
                echo_acc[fn][0] = __builtin_amdgcn_mfma_f32_16x16x16bf16_1k(rt0, pfrag[fn][dblk], echo_acc[fn][0], 0, 0, 0);
                echo_acc[fn][1] = __builtin_amdgcn_mfma_f32_16x16x16bf16_1k(rt1, pfrag[fn][dblk], echo_acc[fn][1], 0, 0, 0);
            }
        }
    }

    // Epilogue: echo^T C-layout (col f = l, rows c = ct*16 + q*4 + r)
    #pragma unroll
    for (int fn = 0; fn < 4; ++fn) {
        const int grow = Mbase + wv * 64 + fn * 16 + l;
        float* rowp = partial + ((size_t)blockIdx.x * N + grow) * 32 + q * 4;
        *(f32x4*)(rowp)      = echo_acc[fn][0];
        *(f32x4*)(rowp + 16) = echo_acc[fn][1];
    }
}

// ---- reduce: sum partials over splits; col<C -> echo, col==C -> intensity ----
__global__ __launch_bounds__(256) void reduce_kernel(const float* __restrict__ partial,
                                                     float* __restrict__ echo,
                                                     float* __restrict__ inten,
                                                     int N, int splits, int C) {
    int t = blockIdx.x * 256 + threadIdx.x;    // N*32 threads
    int row = t >> 5, c = t & 31;
    if (row >= N || c > C) return;
    float s = 0.0f;
    for (int k = 0; k < splits; ++k)
        s += partial[((size_t)k * N + (size_t)row) * 32 + c];
    if (c < C) echo[(size_t)row * C + c] = s;
    else       inten[row] = s;
}

extern "C" void kernel_launch(void* const* d_in, const int* in_sizes, int n_in,
                              void* d_out, int out_size, void* d_ws, size_t ws_size,
                              hipStream_t stream) {
    const int N = in_sizes[0] / HDIM;       // 4096
    const int D = in_sizes[1] / HDIM;       // 16384
    const int C = in_sizes[2] / D;          // 28

    const float* feat = (const float*)d_in[0];
    const float* exf  = (const float*)d_in[1];
    const float* reps = (const float*)d_in[2];
    const int*   p    = (const int*)d_in[3];

    short* Fn = (short*)d_ws;                          // [N][256] bf16 (swizzled)
    short* En = Fn + (size_t)N * HDIM;                 // [D][256] bf16 (swizzled)
    short* Rt = En + (size_t)D * HDIM;                 // [32][D] bf16 (col C = 1.0)
    float* partial = (float*)(Rt + (size_t)32 * D);    // [splits][N][32] f32

    const size_t base_bytes = ((size_t)(N + D) * HDIM + (size_t)32 * D) * 2;
    int splits = NSPLIT_MAX;
    while (splits > 1 &&
           base_bytes + (size_t)splits * N * 32 * 4 > ws_size) splits >>= 1;

    float* echo  = (float*)d_out;
    float* inten = echo + (size_t)N * C;

    const int nb_nrm = (N + D) / 4;
    hipLaunchKernelGGL(prep_kernel, dim3(nb_nrm + D / 128), dim3(256), 0, stream,
                       feat, exf, reps, Fn, Rt, N, N + D, D, C, nb_nrm);

    const int Dchunk = D / splits;
    hipLaunchKernelGGL(fused_kernel, dim3(splits, N / MT), dim3(256), 0, stream,
                       Fn, En, Rt, p, partial, N, D, C, Dchunk);

    hipLaunchKernelGGL(reduce_kernel, dim3(N * 32 / 256), dim3(256), 0, stream,
                       partial, echo, inten, N, splits, C);
}